// Round 1
// 655.843 us; speedup vs baseline: 1.3332x; 1.3332x over previous
//
#include <hip/hip_runtime.h>

#define N_USERS  200000
#define N_ITEMS  100000
#define N_TOTAL  300000
#define EMB_DIM  64
#define N_EDGES  4000000
#define N_LAYERS 3

// generic scan: 1024 elements per scan block
#define SCAN_CHUNK 1024

// radix partition: 512-row buckets, 8192-edge chunks
#define B2_BITS 9
#define B2_ROWS (1 << B2_BITS)                                     // 512
#define NB2 ((N_TOTAL + B2_ROWS - 1) >> B2_BITS)                   // 586
#define CHUNK_E 8192
#define NBLK ((N_EDGES + CHUNK_E - 1) / CHUNK_E)                   // 489
#define NFLAT (NB2 * NBLK)                                         // 286,554
#define NSB_FLAT ((NFLAT + SCAN_CHUNK - 1) / SCAN_CHUNK)           // 280

// edge packing: (local_row[9b] << 19) | dst[19b];  N_TOTAL < 2^19
#define DST_BITS 19
#define DST_MASK ((1 << DST_BITS) - 1)

// ---- bf16 helpers ----
__device__ __forceinline__ unsigned bfpack(float a, float b) {
    unsigned ua = __float_as_uint(a); ua = (ua + 0x7fffu + ((ua >> 16) & 1u)) >> 16;
    unsigned ub = __float_as_uint(b); ub = (ub + 0x7fffu + ((ub >> 16) & 1u)) >> 16;
    return ua | (ub << 16);
}
__device__ __forceinline__ float bflo(unsigned u) { return __uint_as_float(u << 16); }
__device__ __forceinline__ float bfhi(unsigned u) { return __uint_as_float(u & 0xffff0000u); }

// ---------------- generic 3-pass exclusive scan ----------------
__global__ void scanA_g(const int* __restrict__ in, int* __restrict__ out,
                        int* __restrict__ bsums, int n) {
    __shared__ int lds[256];
    int t = threadIdx.x, b = blockIdx.x;
    int base = b * SCAN_CHUNK + t * 4;
    int v[4];
#pragma unroll
    for (int k = 0; k < 4; ++k)
        v[k] = (base + k < n) ? in[base + k] : 0;
    int s = v[0] + v[1] + v[2] + v[3];
    lds[t] = s;
    __syncthreads();
    for (int off = 1; off < 256; off <<= 1) {
        int x = (t >= off) ? lds[t - off] : 0;
        __syncthreads();
        lds[t] += x;
        __syncthreads();
    }
    int inc = lds[t];
    int exc = inc - s;
    if (t == 255) bsums[b] = inc;
    int run = exc;
#pragma unroll
    for (int k = 0; k < 4; ++k) {
        if (base + k < n) out[base + k] = run;
        run += v[k];
    }
}

__global__ void scanB_g(int* __restrict__ bsums, int nb, int* __restrict__ total_out) {
    __shared__ int lds[512];
    int t = threadIdx.x;
    int v = (t < nb) ? bsums[t] : 0;
    lds[t] = v;
    __syncthreads();
    for (int o = 1; o < 512; o <<= 1) {
        int x = (t >= o) ? lds[t - o] : 0;
        __syncthreads();
        lds[t] += x;
        __syncthreads();
    }
    if (t < nb) bsums[t] = lds[t] - v;       // exclusive
    if (total_out && t == nb - 1) *total_out = lds[t];
}

__global__ void scanC_g(int* __restrict__ out, const int* __restrict__ bsums, int n) {
    int i = blockIdx.x * blockDim.x + threadIdx.x;
    if (i < n) out[i] += bsums[i >> 10];
}

// ---- partition phase A: per-(block,bucket) counts via LDS ----
__global__ __launch_bounds__(256) void partA_kernel(const int* __restrict__ src,
                                                    int* __restrict__ bcnt) {
    __shared__ int lcnt[NB2];
    int blk = blockIdx.x, t = threadIdx.x;
    for (int i = t; i < NB2; i += 256) lcnt[i] = 0;
    __syncthreads();
    int base = blk * CHUNK_E;
    int end = base + CHUNK_E; if (end > N_EDGES) end = N_EDGES;
    for (int e = base + t; e < end; e += 256)
        atomicAdd(&lcnt[src[e] >> B2_BITS], 1);
    __syncthreads();
    for (int i = t; i < NB2; i += 256)
        bcnt[(size_t)i * NBLK + blk] = lcnt[i];
}

// ---- partition phase C: write packed edges into block-private ranges ----
__global__ __launch_bounds__(256) void partC_kernel(const int* __restrict__ src,
                                                    const int* __restrict__ dst,
                                                    const int* __restrict__ boffs,
                                                    int* __restrict__ edgebuf) {
    __shared__ int lcur[NB2];
    int blk = blockIdx.x, t = threadIdx.x;
    for (int i = t; i < NB2; i += 256) lcur[i] = boffs[(size_t)i * NBLK + blk];
    __syncthreads();
    int base = blk * CHUNK_E;
    int end = base + CHUNK_E; if (end > N_EDGES) end = N_EDGES;
    for (int e = base + t; e < end; e += 256) {
        int s = src[e], d = dst[e];
        int pos = atomicAdd(&lcur[s >> B2_BITS], 1);
        edgebuf[pos] = ((s & (B2_ROWS - 1)) << DST_BITS) | d;
    }
}

// ---- fused fine pass: per-bucket hist + scan -> offs/dinv, then scatter col ----
// Replaces global hist_kernel + offs scan chain + dinv_kernel.
__global__ __launch_bounds__(256) void part2_kernel(const int* __restrict__ boffs,
                                                    const int* __restrict__ edgebuf,
                                                    int* __restrict__ col,
                                                    int* __restrict__ offs,
                                                    float* __restrict__ dinv) {
    __shared__ int lhist[B2_ROWS];    // counts, then running write cursors
    __shared__ int lsums[256];
    int b = blockIdx.x;
    int base = b << B2_BITS;
    int nrows = N_TOTAL - base; if (nrows > B2_ROWS) nrows = B2_ROWS;
    int t = threadIdx.x;
    int bstart = boffs[(size_t)b * NBLK];
    int eend = (b + 1 < NB2) ? boffs[(size_t)(b + 1) * NBLK] : N_EDGES;

    for (int i = t; i < B2_ROWS; i += 256) lhist[i] = 0;
    __syncthreads();
    // pass 1: per-row counts
    for (int j = bstart + t; j < eend; j += 256)
        atomicAdd(&lhist[edgebuf[j] >> DST_BITS], 1);
    __syncthreads();
    // exclusive scan of 512 counts (2 per thread)
    int v0 = lhist[2 * t], v1 = lhist[2 * t + 1];
    int s = v0 + v1;
    lsums[t] = s;
    __syncthreads();
    for (int o = 1; o < 256; o <<= 1) {
        int x = (t >= o) ? lsums[t - o] : 0;
        __syncthreads();
        lsums[t] += x;
        __syncthreads();
    }
    int exc = lsums[t] - s;                 // exclusive over pairs
    int o0 = bstart + exc;
    int o1 = o0 + v0;
    // global row offsets + dinv (counts == per-row src-degree)
    if (2 * t < nrows) {
        offs[base + 2 * t] = o0;
        dinv[base + 2 * t] = rsqrtf((float)v0 + 1e-8f);
    }
    if (2 * t + 1 < nrows) {
        offs[base + 2 * t + 1] = o1;
        dinv[base + 2 * t + 1] = rsqrtf((float)v1 + 1e-8f);
    }
    if (b == NB2 - 1 && t == 0) offs[N_TOTAL] = N_EDGES;
    // reuse lhist as write cursors
    lhist[2 * t] = o0;
    lhist[2 * t + 1] = o1;
    __syncthreads();
    // pass 2: scatter dst into row-sorted col
    for (int j = bstart + t; j < eend; j += 256) {
        int e = edgebuf[j];
        int r = e >> DST_BITS;
        int pos = atomicAdd(&lhist[r], 1);
        col[pos] = e & DST_MASK;
    }
}

// ---- g0 = dinv ⊙ concat(user_w, item_w), bf16x2 packed; row N_TOTAL = zeros ----
__global__ void convert_kernel(const float2* __restrict__ uw2,
                               const float2* __restrict__ iw2,
                               const float* __restrict__ dinv,
                               unsigned* __restrict__ g0) {
    int i = blockIdx.x * blockDim.x + threadIdx.x;
    const int n = (N_TOTAL + 1) * 32;
    if (i < n) {
        int row = i >> 5;
        if (row >= N_TOTAL) {
            g0[i] = 0u;                      // dummy zero row
        } else {
            float2 x = (row < N_USERS) ? uw2[i] : iw2[i - N_USERS * 32];
            float di = dinv[row];
            g0[i] = bfpack(di * x.x, di * x.y);
        }
    }
}

// ---------------- gather SpMM on pre-scaled g tables ----------------
// h_next[row] = dinv[row] * sum_{edges} g_prev[col];  g_next = dinv * h_next.
// wave = row; lane m handles dims 2m,2m+1.
// New structure: one coalesced load grabs up to 64 col indices for the row;
// indices broadcast via readlane (scalar); 8 independent gathers in flight per
// half-wave per iteration (16 edges/wave-iter). Out-of-range slots read the
// zero row at index N_TOTAL (no masking in the accumulate).
// MODE 0: out = x + h.  MODE 1: out += h.  MODE 2: out = (out+h)/4, no g_next.
template <int MODE>
__global__ __launch_bounds__(256) void gather_kernel(
        const int* __restrict__ offs,
        const int* __restrict__ col,
        const float* __restrict__ dinv,
        const unsigned* __restrict__ gprev,
        unsigned* __restrict__ gnext,
        float2* __restrict__ out2,
        const float2* __restrict__ uw2,
        const float2* __restrict__ iw2) {
    int row  = blockIdx.x * 4 + (threadIdx.x >> 6);
    int lane = threadIdx.x & 63;
    int sub  = lane >> 5;
    int m    = lane & 31;
    // wave-uniform row bounds -> SGPRs (enables scalar loop + readlane)
    int start = __builtin_amdgcn_readfirstlane(offs[row]);
    int end   = __builtin_amdgcn_readfirstlane(offs[row + 1]);
    float a0 = 0.f, a1 = 0.f;
    int kbase = sub << 3;
    for (int cb = start; cb < end; cb += 64) {
        int rem = end - cb;
        int n = rem > 64 ? 64 : rem;
        int myc = (lane < n) ? col[cb + lane] : N_TOTAL;   // one coalesced load
        for (int k0 = 0; k0 < n; k0 += 16) {
            int c[8];
#pragma unroll
            for (int i = 0; i < 8; ++i) {
                int ka = k0 + i;                            // uniform
                int c0 = __builtin_amdgcn_readlane(myc, ka);
                int c1 = __builtin_amdgcn_readlane(myc, ka + 8);
                int cc = sub ? c1 : c0;
                int kk = ka + kbase;                        // this lane's edge id
                c[i] = (kk < n) ? cc : N_TOTAL;             // dummy -> zero row
            }
            unsigned u[8];
#pragma unroll
            for (int i = 0; i < 8; ++i)
                u[i] = gprev[c[i] * 32 + m];                // 8 loads in flight
#pragma unroll
            for (int i = 0; i < 8; ++i) {
                a0 += bflo(u[i]); a1 += bfhi(u[i]);
            }
        }
    }
    a0 += __shfl_xor(a0, 32);
    a1 += __shfl_xor(a1, 32);
    if (sub == 0) {
        float di = dinv[row];
        float h0 = di * a0, h1 = di * a1;
        int p = row * 32 + m;
        if (MODE == 0) {
            float2 x = (row < N_USERS) ? uw2[p] : iw2[p - N_USERS * 32];
            gnext[p] = bfpack(di * h0, di * h1);
            out2[p] = make_float2(x.x + h0, x.y + h1);
        } else if (MODE == 1) {
            float2 o = out2[p];
            gnext[p] = bfpack(di * h0, di * h1);
            out2[p] = make_float2(o.x + h0, o.y + h1);
        } else {
            float2 o = out2[p];
            out2[p] = make_float2((o.x + h0) * 0.25f, (o.y + h1) * 0.25f);
        }
    }
    // maintain the zero row of the table the NEXT kernel gathers from
    if (MODE != 2) {
        if (blockIdx.x == 0 && threadIdx.x < 32)
            gnext[N_TOTAL * 32 + threadIdx.x] = 0u;
    }
}

extern "C" void kernel_launch(void* const* d_in, const int* in_sizes, int n_in,
                              void* d_out, int out_size, void* d_ws, size_t ws_size,
                              hipStream_t stream) {
    const float* user_w = (const float*)d_in[0];
    const float* item_w = (const float*)d_in[1];
    const int*   src    = (const int*)d_in[2];
    const int*   dst    = (const int*)d_in[3];
    float* out = (float*)d_out;
    (void)in_sizes; (void)n_in; (void)out_size; (void)ws_size;

    char* ws = (char*)d_ws;
    size_t off = 0;
    auto alloc = [&](size_t bytes) {
        char* p = ws + off;
        off = (off + bytes + 255) & ~(size_t)255;
        return p;
    };
    int*      offs   = (int*)     alloc((size_t)(N_TOTAL + 1) * 4);
    int*      bcnt   = (int*)     alloc((size_t)NFLAT * 4);              // 1.15 MB
    int*      boffs  = (int*)     alloc((size_t)NFLAT * 4);              // 1.15 MB
    int*      bs2    = (int*)     alloc((size_t)NSB_FLAT * 4);
    int*      col    = (int*)     alloc((size_t)N_EDGES * 4);            // 16 MB
    int*      edgebuf= (int*)     alloc((size_t)N_EDGES * 4);            // 16 MB (packed)
    float*    dinv   = (float*)   alloc((size_t)N_TOTAL * 4);
    unsigned* g0     = (unsigned*)alloc((size_t)(N_TOTAL + 1) * 32 * 4); // 38.4 MB
    unsigned* g_a    = (unsigned*)alloc((size_t)(N_TOTAL + 1) * 32 * 4); // 38.4 MB
    unsigned* g_b    = (unsigned*)alloc((size_t)(N_TOTAL + 1) * 32 * 4); // 38.4 MB

    const int B = 256;
    const int gatherGrid = N_TOTAL / 4;   // 75000

    // radix partition into 512-row buckets (block-private write ranges)
    partA_kernel<<<NBLK, B, 0, stream>>>(src, bcnt);
    scanA_g<<<NSB_FLAT, B, 0, stream>>>(bcnt, boffs, bs2, NFLAT);
    scanB_g<<<1, 512, 0, stream>>>(bs2, NSB_FLAT, nullptr);
    scanC_g<<<(NFLAT + B - 1) / B, B, 0, stream>>>(boffs, bs2, NFLAT);
    partC_kernel<<<NBLK, B, 0, stream>>>(src, dst, boffs, edgebuf);
    // fused: per-bucket hist + scan -> offs, dinv; scatter col
    part2_kernel<<<NB2, B, 0, stream>>>(boffs, edgebuf, col, offs, dinv);

    // g0 = dinv * x (bf16), plus zero dummy row
    convert_kernel<<<((N_TOTAL + 1) * 32 + B - 1) / B, B, 0, stream>>>(
        (const float2*)user_w, (const float2*)item_w, dinv, g0);

    const float2* uw2 = (const float2*)user_w;
    const float2* iw2 = (const float2*)item_w;
    float2* out2 = (float2*)out;
    gather_kernel<0><<<gatherGrid, B, 0, stream>>>(offs, col, dinv, g0,  g_a, out2, uw2, iw2);
    gather_kernel<1><<<gatherGrid, B, 0, stream>>>(offs, col, dinv, g_a, g_b, out2, uw2, iw2);
    gather_kernel<2><<<gatherGrid, B, 0, stream>>>(offs, col, dinv, g_b, nullptr, out2, uw2, iw2);
}

// Round 2
// 618.172 us; speedup vs baseline: 1.4144x; 1.0609x over previous
//
#include <hip/hip_runtime.h>

#define N_USERS  200000
#define N_ITEMS  100000
#define N_TOTAL  300000
#define EMB_DIM  64
#define N_EDGES  4000000
#define N_LAYERS 3

// generic scan: 1024 elements per scan block
#define SCAN_CHUNK 1024

// radix partition: 512-row buckets, 8192-edge chunks
#define B2_BITS 9
#define B2_ROWS (1 << B2_BITS)                                     // 512
#define NB2 ((N_TOTAL + B2_ROWS - 1) >> B2_BITS)                   // 586
#define CHUNK_E 8192
#define NBLK ((N_EDGES + CHUNK_E - 1) / CHUNK_E)                   // 489
#define NFLAT (NB2 * NBLK)                                         // 286,554
#define NSB_FLAT ((NFLAT + SCAN_CHUNK - 1) / SCAN_CHUNK)           // 280

// edge packing: (local_row[9b] << 19) | dst[19b];  N_TOTAL < 2^19
#define DST_BITS 19
#define DST_MASK ((1 << DST_BITS) - 1)

typedef float f32x2 __attribute__((ext_vector_type(2)));

// ---- bf16 helpers ----
__device__ __forceinline__ unsigned bfpack(float a, float b) {
    unsigned ua = __float_as_uint(a); ua = (ua + 0x7fffu + ((ua >> 16) & 1u)) >> 16;
    unsigned ub = __float_as_uint(b); ub = (ub + 0x7fffu + ((ub >> 16) & 1u)) >> 16;
    return ua | (ub << 16);
}
__device__ __forceinline__ float bflo(unsigned u) { return __uint_as_float(u << 16); }
__device__ __forceinline__ float bfhi(unsigned u) { return __uint_as_float(u & 0xffff0000u); }
__device__ __forceinline__ f32x2 bf2(unsigned u) {
    f32x2 t; t.x = bflo(u); t.y = bfhi(u); return t;   // candidates for v_pk_add_f32 fusion
}

// ---------------- generic 3-pass exclusive scan ----------------
__global__ void scanA_g(const int* __restrict__ in, int* __restrict__ out,
                        int* __restrict__ bsums, int n) {
    __shared__ int lds[256];
    int t = threadIdx.x, b = blockIdx.x;
    int base = b * SCAN_CHUNK + t * 4;
    int v[4];
#pragma unroll
    for (int k = 0; k < 4; ++k)
        v[k] = (base + k < n) ? in[base + k] : 0;
    int s = v[0] + v[1] + v[2] + v[3];
    lds[t] = s;
    __syncthreads();
    for (int off = 1; off < 256; off <<= 1) {
        int x = (t >= off) ? lds[t - off] : 0;
        __syncthreads();
        lds[t] += x;
        __syncthreads();
    }
    int inc = lds[t];
    int exc = inc - s;
    if (t == 255) bsums[b] = inc;
    int run = exc;
#pragma unroll
    for (int k = 0; k < 4; ++k) {
        if (base + k < n) out[base + k] = run;
        run += v[k];
    }
}

__global__ void scanB_g(int* __restrict__ bsums, int nb, int* __restrict__ total_out) {
    __shared__ int lds[512];
    int t = threadIdx.x;
    int v = (t < nb) ? bsums[t] : 0;
    lds[t] = v;
    __syncthreads();
    for (int o = 1; o < 512; o <<= 1) {
        int x = (t >= o) ? lds[t - o] : 0;
        __syncthreads();
        lds[t] += x;
        __syncthreads();
    }
    if (t < nb) bsums[t] = lds[t] - v;       // exclusive
    if (total_out && t == nb - 1) *total_out = lds[t];
}

__global__ void scanC_g(int* __restrict__ out, const int* __restrict__ bsums, int n) {
    int i = blockIdx.x * blockDim.x + threadIdx.x;
    if (i < n) out[i] += bsums[i >> 10];
}

// ---- partition phase A: per-(block,bucket) counts via LDS ----
__global__ __launch_bounds__(256) void partA_kernel(const int* __restrict__ src,
                                                    int* __restrict__ bcnt) {
    __shared__ int lcnt[NB2];
    int blk = blockIdx.x, t = threadIdx.x;
    for (int i = t; i < NB2; i += 256) lcnt[i] = 0;
    __syncthreads();
    int base = blk * CHUNK_E;
    int end = base + CHUNK_E; if (end > N_EDGES) end = N_EDGES;
    for (int e = base + t; e < end; e += 256)
        atomicAdd(&lcnt[src[e] >> B2_BITS], 1);
    __syncthreads();
    for (int i = t; i < NB2; i += 256)
        bcnt[(size_t)i * NBLK + blk] = lcnt[i];
}

// ---- partition phase C: write packed edges into block-private ranges ----
__global__ __launch_bounds__(256) void partC_kernel(const int* __restrict__ src,
                                                    const int* __restrict__ dst,
                                                    const int* __restrict__ boffs,
                                                    int* __restrict__ edgebuf) {
    __shared__ int lcur[NB2];
    int blk = blockIdx.x, t = threadIdx.x;
    for (int i = t; i < NB2; i += 256) lcur[i] = boffs[(size_t)i * NBLK + blk];
    __syncthreads();
    int base = blk * CHUNK_E;
    int end = base + CHUNK_E; if (end > N_EDGES) end = N_EDGES;
    for (int e = base + t; e < end; e += 256) {
        int s = src[e], d = dst[e];
        int pos = atomicAdd(&lcur[s >> B2_BITS], 1);
        edgebuf[pos] = ((s & (B2_ROWS - 1)) << DST_BITS) | d;
    }
}

// ---- fused fine pass: per-bucket hist + scan -> offs/dinv, then scatter col ----
__global__ __launch_bounds__(256) void part2_kernel(const int* __restrict__ boffs,
                                                    const int* __restrict__ edgebuf,
                                                    int* __restrict__ col,
                                                    int* __restrict__ offs,
                                                    float* __restrict__ dinv) {
    __shared__ int lhist[B2_ROWS];    // counts, then running write cursors
    __shared__ int lsums[256];
    int b = blockIdx.x;
    int base = b << B2_BITS;
    int nrows = N_TOTAL - base; if (nrows > B2_ROWS) nrows = B2_ROWS;
    int t = threadIdx.x;
    int bstart = boffs[(size_t)b * NBLK];
    int eend = (b + 1 < NB2) ? boffs[(size_t)(b + 1) * NBLK] : N_EDGES;

    for (int i = t; i < B2_ROWS; i += 256) lhist[i] = 0;
    __syncthreads();
    // pass 1: per-row counts
    for (int j = bstart + t; j < eend; j += 256)
        atomicAdd(&lhist[edgebuf[j] >> DST_BITS], 1);
    __syncthreads();
    // exclusive scan of 512 counts (2 per thread)
    int v0 = lhist[2 * t], v1 = lhist[2 * t + 1];
    int s = v0 + v1;
    lsums[t] = s;
    __syncthreads();
    for (int o = 1; o < 256; o <<= 1) {
        int x = (t >= o) ? lsums[t - o] : 0;
        __syncthreads();
        lsums[t] += x;
        __syncthreads();
    }
    int exc = lsums[t] - s;                 // exclusive over pairs
    int o0 = bstart + exc;
    int o1 = o0 + v0;
    // global row offsets + dinv (counts == per-row src-degree)
    if (2 * t < nrows) {
        offs[base + 2 * t] = o0;
        dinv[base + 2 * t] = rsqrtf((float)v0 + 1e-8f);
    }
    if (2 * t + 1 < nrows) {
        offs[base + 2 * t + 1] = o1;
        dinv[base + 2 * t + 1] = rsqrtf((float)v1 + 1e-8f);
    }
    if (b == NB2 - 1 && t == 0) offs[N_TOTAL] = N_EDGES;
    // reuse lhist as write cursors
    lhist[2 * t] = o0;
    lhist[2 * t + 1] = o1;
    __syncthreads();
    // pass 2: scatter dst into row-sorted col
    for (int j = bstart + t; j < eend; j += 256) {
        int e = edgebuf[j];
        int r = e >> DST_BITS;
        int pos = atomicAdd(&lhist[r], 1);
        col[pos] = e & DST_MASK;
    }
}

// ---- g0 = dinv ⊙ concat(user_w, item_w), bf16x2 packed; row N_TOTAL = zeros ----
__global__ void convert_kernel(const float2* __restrict__ uw2,
                               const float2* __restrict__ iw2,
                               const float* __restrict__ dinv,
                               unsigned* __restrict__ g0) {
    int i = blockIdx.x * blockDim.x + threadIdx.x;
    const int n = (N_TOTAL + 1) * 32;
    if (i < n) {
        int row = i >> 5;
        if (row >= N_TOTAL) {
            g0[i] = 0u;                      // dummy zero row
        } else {
            float2 x = (row < N_USERS) ? uw2[i] : iw2[i - N_USERS * 32];
            float di = dinv[row];
            g0[i] = bfpack(di * x.x, di * x.y);
        }
    }
}

// ---------------- gather SpMM on pre-scaled g tables ----------------
// h_next[row] = dinv[row] * sum_{edges} g_prev[col];  g_next = dinv * h_next.
// wave = row. 4 edge streams (16-lane quarters); lane r of quarter q covers
// dims 4r..4r+3 via one dwordx2 load (128B per quarter-gather = one row).
// Index broadcast: single ds_bpermute (__shfl) per edge, no bounds selects —
// out-of-range slots read the zero row at index N_TOTAL.
// MODE 0: out = x + h.  MODE 1: out += h.  MODE 2: out = (out+h)/4, no g_next.
template <int MODE>
__global__ __launch_bounds__(256) void gather_kernel(
        const int* __restrict__ offs,
        const int* __restrict__ col,
        const float* __restrict__ dinv,
        const unsigned* __restrict__ gprev,
        unsigned* __restrict__ gnext,
        float4* __restrict__ out4,
        const float4* __restrict__ uw4,
        const float4* __restrict__ iw4) {
    int row  = blockIdx.x * 4 + (threadIdx.x >> 6);
    int lane = threadIdx.x & 63;
    int q    = lane >> 4;          // quarter = edge stream
    int r    = lane & 15;          // dims 4r..4r+3
    // wave-uniform row bounds -> SGPRs
    int start = __builtin_amdgcn_readfirstlane(offs[row]);
    int end   = __builtin_amdgcn_readfirstlane(offs[row + 1]);
    f32x2 acc01 = {0.f, 0.f};
    f32x2 acc23 = {0.f, 0.f};
    for (int cb = start; cb < end; cb += 64) {
        int rem = end - cb;
        int n = rem > 64 ? 64 : rem;
        int myc = (lane < rem) ? col[cb + lane] : N_TOTAL;   // one coalesced load
        for (int k0 = 0; k0 < n; k0 += 8) {
            int c0 = __shfl(myc, k0 + q);          // edges k0+q, k0+4+q
            int c1 = __shfl(myc, k0 + 4 + q);
            uint2 u0 = *(const uint2*)(gprev + ((size_t)(unsigned)c0 << 5) + 2 * r);
            uint2 u1 = *(const uint2*)(gprev + ((size_t)(unsigned)c1 << 5) + 2 * r);
            acc01 += bf2(u0.x); acc23 += bf2(u0.y);
            acc01 += bf2(u1.x); acc23 += bf2(u1.y);
        }
    }
    float a0 = acc01.x, a1 = acc01.y, a2 = acc23.x, a3 = acc23.y;
    a0 += __shfl_xor(a0, 16);
    a1 += __shfl_xor(a1, 16);
    a2 += __shfl_xor(a2, 16);
    a3 += __shfl_xor(a3, 16);
    a0 += __shfl_xor(a0, 32);
    a1 += __shfl_xor(a1, 32);
    a2 += __shfl_xor(a2, 32);
    a3 += __shfl_xor(a3, 32);
    if (lane < 16) {
        float di = dinv[row];
        float h0 = di * a0, h1 = di * a1, h2 = di * a2, h3 = di * a3;
        int p = row * 16 + r;
        if (MODE == 0) {
            float4 x = (row < N_USERS) ? uw4[p] : iw4[p - N_USERS * 16];
            ((uint2*)gnext)[p] = make_uint2(bfpack(di * h0, di * h1),
                                            bfpack(di * h2, di * h3));
            out4[p] = make_float4(x.x + h0, x.y + h1, x.z + h2, x.w + h3);
        } else if (MODE == 1) {
            float4 o = out4[p];
            ((uint2*)gnext)[p] = make_uint2(bfpack(di * h0, di * h1),
                                            bfpack(di * h2, di * h3));
            out4[p] = make_float4(o.x + h0, o.y + h1, o.z + h2, o.w + h3);
        } else {
            float4 o = out4[p];
            out4[p] = make_float4((o.x + h0) * 0.25f, (o.y + h1) * 0.25f,
                                  (o.z + h2) * 0.25f, (o.w + h3) * 0.25f);
        }
    }
    // maintain the zero row of the table the NEXT kernel gathers from
    if (MODE != 2) {
        if (blockIdx.x == 0 && threadIdx.x < 32)
            gnext[N_TOTAL * 32 + threadIdx.x] = 0u;
    }
}

extern "C" void kernel_launch(void* const* d_in, const int* in_sizes, int n_in,
                              void* d_out, int out_size, void* d_ws, size_t ws_size,
                              hipStream_t stream) {
    const float* user_w = (const float*)d_in[0];
    const float* item_w = (const float*)d_in[1];
    const int*   src    = (const int*)d_in[2];
    const int*   dst    = (const int*)d_in[3];
    float* out = (float*)d_out;
    (void)in_sizes; (void)n_in; (void)out_size; (void)ws_size;

    char* ws = (char*)d_ws;
    size_t off = 0;
    auto alloc = [&](size_t bytes) {
        char* p = ws + off;
        off = (off + bytes + 255) & ~(size_t)255;
        return p;
    };
    int*      offs   = (int*)     alloc((size_t)(N_TOTAL + 1) * 4);
    int*      bcnt   = (int*)     alloc((size_t)NFLAT * 4);              // 1.15 MB
    int*      boffs  = (int*)     alloc((size_t)NFLAT * 4);              // 1.15 MB
    int*      bs2    = (int*)     alloc((size_t)NSB_FLAT * 4);
    int*      col    = (int*)     alloc((size_t)N_EDGES * 4);            // 16 MB
    int*      edgebuf= (int*)     alloc((size_t)N_EDGES * 4);            // 16 MB (packed)
    float*    dinv   = (float*)   alloc((size_t)N_TOTAL * 4);
    unsigned* g0     = (unsigned*)alloc((size_t)(N_TOTAL + 1) * 32 * 4); // 38.4 MB
    unsigned* g_a    = (unsigned*)alloc((size_t)(N_TOTAL + 1) * 32 * 4); // 38.4 MB
    unsigned* g_b    = (unsigned*)alloc((size_t)(N_TOTAL + 1) * 32 * 4); // 38.4 MB

    const int B = 256;
    const int gatherGrid = N_TOTAL / 4;   // 75000

    // radix partition into 512-row buckets (block-private write ranges)
    partA_kernel<<<NBLK, B, 0, stream>>>(src, bcnt);
    scanA_g<<<NSB_FLAT, B, 0, stream>>>(bcnt, boffs, bs2, NFLAT);
    scanB_g<<<1, 512, 0, stream>>>(bs2, NSB_FLAT, nullptr);
    scanC_g<<<(NFLAT + B - 1) / B, B, 0, stream>>>(boffs, bs2, NFLAT);
    partC_kernel<<<NBLK, B, 0, stream>>>(src, dst, boffs, edgebuf);
    // fused: per-bucket hist + scan -> offs, dinv; scatter col
    part2_kernel<<<NB2, B, 0, stream>>>(boffs, edgebuf, col, offs, dinv);

    // g0 = dinv * x (bf16), plus zero dummy row
    convert_kernel<<<((N_TOTAL + 1) * 32 + B - 1) / B, B, 0, stream>>>(
        (const float2*)user_w, (const float2*)item_w, dinv, g0);

    const float4* uw4 = (const float4*)user_w;
    const float4* iw4 = (const float4*)item_w;
    float4* out4 = (float4*)out;
    gather_kernel<0><<<gatherGrid, B, 0, stream>>>(offs, col, dinv, g0,  g_a, out4, uw4, iw4);
    gather_kernel<1><<<gatherGrid, B, 0, stream>>>(offs, col, dinv, g_a, g_b, out4, uw4, iw4);
    gather_kernel<2><<<gatherGrid, B, 0, stream>>>(offs, col, dinv, g_b, nullptr, out4, uw4, iw4);
}

// Round 3
// 573.869 us; speedup vs baseline: 1.5236x; 1.0772x over previous
//
#include <hip/hip_runtime.h>

#define N_USERS  200000
#define N_ITEMS  100000
#define N_TOTAL  300000
#define EMB_DIM  64
#define N_EDGES  4000000
#define N_LAYERS 3

// generic scan: 1024 elements per scan block
#define SCAN_CHUNK 1024

// radix partition: 512-row buckets, 8192-edge chunks
#define B2_BITS 9
#define B2_ROWS (1 << B2_BITS)                                     // 512
#define NB2 ((N_TOTAL + B2_ROWS - 1) >> B2_BITS)                   // 586
#define CHUNK_E 8192
#define NBLK ((N_EDGES + CHUNK_E - 1) / CHUNK_E)                   // 489
#define NFLAT (NB2 * NBLK)                                         // 286,554
#define NSB_FLAT ((NFLAT + SCAN_CHUNK - 1) / SCAN_CHUNK)           // 280

// edge packing: (local_row[9b] << 19) | dst[19b];  N_TOTAL < 2^19
#define DST_BITS 19
#define DST_MASK ((1 << DST_BITS) - 1)

typedef float f32x2 __attribute__((ext_vector_type(2)));

// ---- bf16 helpers ----
__device__ __forceinline__ unsigned bfpack(float a, float b) {
    unsigned ua = __float_as_uint(a); ua = (ua + 0x7fffu + ((ua >> 16) & 1u)) >> 16;
    unsigned ub = __float_as_uint(b); ub = (ub + 0x7fffu + ((ub >> 16) & 1u)) >> 16;
    return ua | (ub << 16);
}
__device__ __forceinline__ float bflo(unsigned u) { return __uint_as_float(u << 16); }
__device__ __forceinline__ float bfhi(unsigned u) { return __uint_as_float(u & 0xffff0000u); }
__device__ __forceinline__ f32x2 bf2(unsigned u) {
    f32x2 t; t.x = bflo(u); t.y = bfhi(u); return t;   // candidates for v_pk_add_f32 fusion
}

// ---------------- 2-level scan (block-sum correction folded into consumers) ----
__global__ void scanA_g(const int* __restrict__ in, int* __restrict__ out,
                        int* __restrict__ bsums, int n) {
    __shared__ int lds[256];
    int t = threadIdx.x, b = blockIdx.x;
    int base = b * SCAN_CHUNK + t * 4;
    int v[4];
#pragma unroll
    for (int k = 0; k < 4; ++k)
        v[k] = (base + k < n) ? in[base + k] : 0;
    int s = v[0] + v[1] + v[2] + v[3];
    lds[t] = s;
    __syncthreads();
    for (int off = 1; off < 256; off <<= 1) {
        int x = (t >= off) ? lds[t - off] : 0;
        __syncthreads();
        lds[t] += x;
        __syncthreads();
    }
    int inc = lds[t];
    int exc = inc - s;
    if (t == 255) bsums[b] = inc;
    int run = exc;
#pragma unroll
    for (int k = 0; k < 4; ++k) {
        if (base + k < n) out[base + k] = run;
        run += v[k];
    }
}

__global__ void scanB_g(int* __restrict__ bsums, int nb, int* __restrict__ total_out) {
    __shared__ int lds[512];
    int t = threadIdx.x;
    int v = (t < nb) ? bsums[t] : 0;
    lds[t] = v;
    __syncthreads();
    for (int o = 1; o < 512; o <<= 1) {
        int x = (t >= o) ? lds[t - o] : 0;
        __syncthreads();
        lds[t] += x;
        __syncthreads();
    }
    if (t < nb) bsums[t] = lds[t] - v;       // exclusive
    if (total_out && t == nb - 1) *total_out = lds[t];
}

// ---- partition phase A: per-(block,bucket) counts via LDS; int4 edge loads ----
__global__ __launch_bounds__(512) void partA_kernel(const int* __restrict__ src,
                                                    int* __restrict__ bcnt) {
    __shared__ int lcnt[NB2];
    int blk = blockIdx.x, t = threadIdx.x;
    for (int i = t; i < NB2; i += 512) lcnt[i] = 0;
    __syncthreads();
    int base = blk * CHUNK_E;
    int end = base + CHUNK_E; if (end > N_EDGES) end = N_EDGES;
    for (int e = base + 4 * t; e < end; e += 4 * 512) {
        int4 s4 = *(const int4*)(src + e);
        atomicAdd(&lcnt[s4.x >> B2_BITS], 1);
        atomicAdd(&lcnt[s4.y >> B2_BITS], 1);
        atomicAdd(&lcnt[s4.z >> B2_BITS], 1);
        atomicAdd(&lcnt[s4.w >> B2_BITS], 1);
    }
    __syncthreads();
    for (int i = t; i < NB2; i += 512)
        bcnt[(size_t)i * NBLK + blk] = lcnt[i];
}

// ---- partition phase C: write packed edges into block-private ranges ----
__global__ __launch_bounds__(512) void partC_kernel(const int* __restrict__ src,
                                                    const int* __restrict__ dst,
                                                    const int* __restrict__ boffs,
                                                    const int* __restrict__ bs2,
                                                    int* __restrict__ edgebuf) {
    __shared__ int lcur[NB2];
    int blk = blockIdx.x, t = threadIdx.x;
    for (int i = t; i < NB2; i += 512) {
        size_t f = (size_t)i * NBLK + blk;
        lcur[i] = boffs[f] + bs2[f >> 10];           // folded scanC
    }
    __syncthreads();
    int base = blk * CHUNK_E;
    int end = base + CHUNK_E; if (end > N_EDGES) end = N_EDGES;
    for (int e = base + 2 * t; e < end; e += 2 * 512) {
        int2 s2 = *(const int2*)(src + e);
        int2 d2 = *(const int2*)(dst + e);
        int pos0 = atomicAdd(&lcur[s2.x >> B2_BITS], 1);
        edgebuf[pos0] = ((s2.x & (B2_ROWS - 1)) << DST_BITS) | d2.x;
        int pos1 = atomicAdd(&lcur[s2.y >> B2_BITS], 1);
        edgebuf[pos1] = ((s2.y & (B2_ROWS - 1)) << DST_BITS) | d2.y;
    }
}

// ---- fused fine pass: per-bucket hist + scan -> offs/dinv, then scatter col ----
__global__ __launch_bounds__(512) void part2_kernel(const int* __restrict__ boffs,
                                                    const int* __restrict__ bs2,
                                                    const int* __restrict__ edgebuf,
                                                    int* __restrict__ col,
                                                    int* __restrict__ offs,
                                                    float* __restrict__ dinv) {
    __shared__ int lhist[B2_ROWS];    // counts, then running write cursors
    __shared__ int lsums[512];
    int b = blockIdx.x;
    int base = b << B2_BITS;
    int nrows = N_TOTAL - base; if (nrows > B2_ROWS) nrows = B2_ROWS;
    int t = threadIdx.x;
    size_t f0 = (size_t)b * NBLK;
    int bstart = boffs[f0] + bs2[f0 >> 10];
    int eend;
    if (b + 1 < NB2) {
        size_t f1 = (size_t)(b + 1) * NBLK;
        eend = boffs[f1] + bs2[f1 >> 10];
    } else eend = N_EDGES;

    if (t < B2_ROWS) lhist[t] = 0;
    __syncthreads();
    // pass 1: per-row counts
    for (int j = bstart + t; j < eend; j += 512)
        atomicAdd(&lhist[edgebuf[j] >> DST_BITS], 1);
    __syncthreads();
    // exclusive scan of 512 counts (1 per thread)
    int v = lhist[t];
    lsums[t] = v;
    __syncthreads();
    for (int o = 1; o < 512; o <<= 1) {
        int x = (t >= o) ? lsums[t - o] : 0;
        __syncthreads();
        lsums[t] += x;
        __syncthreads();
    }
    int o0 = bstart + lsums[t] - v;         // exclusive
    if (t < nrows) {
        offs[base + t] = o0;
        dinv[base + t] = rsqrtf((float)v + 1e-8f);
    }
    if (b == NB2 - 1 && t == 0) offs[N_TOTAL] = N_EDGES;
    // reuse lhist as write cursors
    lhist[t] = o0;
    __syncthreads();
    // pass 2: scatter dst into row-sorted col
    for (int j = bstart + t; j < eend; j += 512) {
        int e = edgebuf[j];
        int pos = atomicAdd(&lhist[e >> DST_BITS], 1);
        col[pos] = e & DST_MASK;
    }
}

// ---- g0 = dinv ⊙ concat(user_w, item_w), bf16x2 packed; row N_TOTAL = zeros ----
__global__ void convert_kernel(const float4* __restrict__ uw4,
                               const float4* __restrict__ iw4,
                               const float* __restrict__ dinv,
                               uint2* __restrict__ g0) {
    int i = blockIdx.x * blockDim.x + threadIdx.x;
    const int n = (N_TOTAL + 1) * 16;
    if (i < n) {
        int row = i >> 4;
        if (row >= N_TOTAL) {
            g0[i] = make_uint2(0u, 0u);      // dummy zero row
        } else {
            float4 x = (row < N_USERS) ? uw4[i] : iw4[i - N_USERS * 16];
            float di = dinv[row];
            g0[i] = make_uint2(bfpack(di * x.x, di * x.y),
                               bfpack(di * x.z, di * x.w));
        }
    }
}

// ---------------- gather SpMM on pre-scaled g tables ----------------
// h_next[row] = dinv[row] * sum_{edges} g_prev[col];  g_next = dinv * h_next.
// wave = row. 4 edge streams (16-lane quarters); lane r of quarter q covers
// dims 4r..4r+3 via one dwordx2 load. 16 edges per inner iter => 4 independent
// gathers in flight per wave (latency hiding). Out-of-range shfl slots hold the
// zero-row index N_TOTAL, so the rounded-up tail needs no bounds logic.
// MODE 0: out = x + h.  MODE 1: out += h.  MODE 2: out = (out+h)/4, no g_next.
template <int MODE>
__global__ __launch_bounds__(256) void gather_kernel(
        const int* __restrict__ offs,
        const int* __restrict__ col,
        const float* __restrict__ dinv,
        const unsigned* __restrict__ gprev,
        unsigned* __restrict__ gnext,
        float4* __restrict__ out4,
        const float4* __restrict__ uw4,
        const float4* __restrict__ iw4) {
    int row  = blockIdx.x * 4 + (threadIdx.x >> 6);
    int lane = threadIdx.x & 63;
    int q    = lane >> 4;          // quarter = edge stream
    int r    = lane & 15;          // dims 4r..4r+3
    // wave-uniform row bounds -> SGPRs
    int start = __builtin_amdgcn_readfirstlane(offs[row]);
    int end   = __builtin_amdgcn_readfirstlane(offs[row + 1]);
    float di  = dinv[row];                       // hoisted, hides under loop
    f32x2 acc01 = {0.f, 0.f};
    f32x2 acc23 = {0.f, 0.f};
    for (int cb = start; cb < end; cb += 64) {
        int rem = end - cb;
        int n = rem > 64 ? 64 : rem;
        int myc = (lane < rem) ? col[cb + lane] : N_TOTAL;   // one coalesced load
        for (int k0 = 0; k0 < n; k0 += 16) {
            int c0 = __shfl(myc, k0 + q);
            int c1 = __shfl(myc, k0 + 4 + q);
            int c2 = __shfl(myc, k0 + 8 + q);
            int c3 = __shfl(myc, k0 + 12 + q);
            uint2 u0 = *(const uint2*)(gprev + ((size_t)(unsigned)c0 << 5) + 2 * r);
            uint2 u1 = *(const uint2*)(gprev + ((size_t)(unsigned)c1 << 5) + 2 * r);
            uint2 u2 = *(const uint2*)(gprev + ((size_t)(unsigned)c2 << 5) + 2 * r);
            uint2 u3 = *(const uint2*)(gprev + ((size_t)(unsigned)c3 << 5) + 2 * r);
            acc01 += bf2(u0.x); acc23 += bf2(u0.y);
            acc01 += bf2(u1.x); acc23 += bf2(u1.y);
            acc01 += bf2(u2.x); acc23 += bf2(u2.y);
            acc01 += bf2(u3.x); acc23 += bf2(u3.y);
        }
    }
    float a0 = acc01.x, a1 = acc01.y, a2 = acc23.x, a3 = acc23.y;
    a0 += __shfl_xor(a0, 16);
    a1 += __shfl_xor(a1, 16);
    a2 += __shfl_xor(a2, 16);
    a3 += __shfl_xor(a3, 16);
    a0 += __shfl_xor(a0, 32);
    a1 += __shfl_xor(a1, 32);
    a2 += __shfl_xor(a2, 32);
    a3 += __shfl_xor(a3, 32);
    if (lane < 16) {
        float h0 = di * a0, h1 = di * a1, h2 = di * a2, h3 = di * a3;
        int p = row * 16 + r;
        if (MODE == 0) {
            float4 x = (row < N_USERS) ? uw4[p] : iw4[p - N_USERS * 16];
            ((uint2*)gnext)[p] = make_uint2(bfpack(di * h0, di * h1),
                                            bfpack(di * h2, di * h3));
            out4[p] = make_float4(x.x + h0, x.y + h1, x.z + h2, x.w + h3);
        } else if (MODE == 1) {
            float4 o = out4[p];
            ((uint2*)gnext)[p] = make_uint2(bfpack(di * h0, di * h1),
                                            bfpack(di * h2, di * h3));
            out4[p] = make_float4(o.x + h0, o.y + h1, o.z + h2, o.w + h3);
        } else {
            float4 o = out4[p];
            out4[p] = make_float4((o.x + h0) * 0.25f, (o.y + h1) * 0.25f,
                                  (o.z + h2) * 0.25f, (o.w + h3) * 0.25f);
        }
    }
    // maintain the zero row of the table the NEXT kernel gathers from
    if (MODE != 2) {
        if (blockIdx.x == 0 && threadIdx.x < 32)
            gnext[N_TOTAL * 32 + threadIdx.x] = 0u;
    }
}

extern "C" void kernel_launch(void* const* d_in, const int* in_sizes, int n_in,
                              void* d_out, int out_size, void* d_ws, size_t ws_size,
                              hipStream_t stream) {
    const float* user_w = (const float*)d_in[0];
    const float* item_w = (const float*)d_in[1];
    const int*   src    = (const int*)d_in[2];
    const int*   dst    = (const int*)d_in[3];
    float* out = (float*)d_out;
    (void)in_sizes; (void)n_in; (void)out_size; (void)ws_size;

    char* ws = (char*)d_ws;
    size_t off = 0;
    auto alloc = [&](size_t bytes) {
        char* p = ws + off;
        off = (off + bytes + 255) & ~(size_t)255;
        return p;
    };
    int*      offs   = (int*)     alloc((size_t)(N_TOTAL + 1) * 4);
    int*      bcnt   = (int*)     alloc((size_t)NFLAT * 4);              // 1.15 MB
    int*      boffs  = (int*)     alloc((size_t)NFLAT * 4);              // 1.15 MB
    int*      bs2    = (int*)     alloc((size_t)NSB_FLAT * 4);
    int*      col    = (int*)     alloc((size_t)N_EDGES * 4);            // 16 MB
    int*      edgebuf= (int*)     alloc((size_t)N_EDGES * 4);            // 16 MB (packed)
    float*    dinv   = (float*)   alloc((size_t)N_TOTAL * 4);
    unsigned* g0     = (unsigned*)alloc((size_t)(N_TOTAL + 1) * 32 * 4); // 38.4 MB
    unsigned* g_a    = (unsigned*)alloc((size_t)(N_TOTAL + 1) * 32 * 4); // 38.4 MB
    unsigned* g_b    = (unsigned*)alloc((size_t)(N_TOTAL + 1) * 32 * 4); // 38.4 MB

    const int B = 256;
    const int gatherGrid = N_TOTAL / 4;   // 75000

    // radix partition into 512-row buckets (block-private write ranges)
    partA_kernel<<<NBLK, 512, 0, stream>>>(src, bcnt);
    scanA_g<<<NSB_FLAT, B, 0, stream>>>(bcnt, boffs, bs2, NFLAT);
    scanB_g<<<1, 512, 0, stream>>>(bs2, NSB_FLAT, nullptr);
    partC_kernel<<<NBLK, 512, 0, stream>>>(src, dst, boffs, bs2, edgebuf);
    // fused: per-bucket hist + scan -> offs, dinv; scatter col
    part2_kernel<<<NB2, 512, 0, stream>>>(boffs, bs2, edgebuf, col, offs, dinv);

    // g0 = dinv * x (bf16), plus zero dummy row
    convert_kernel<<<((N_TOTAL + 1) * 16 + B - 1) / B, B, 0, stream>>>(
        (const float4*)user_w, (const float4*)item_w, dinv, (uint2*)g0);

    const float4* uw4 = (const float4*)user_w;
    const float4* iw4 = (const float4*)item_w;
    float4* out4 = (float4*)out;
    gather_kernel<0><<<gatherGrid, B, 0, stream>>>(offs, col, dinv, g0,  g_a, out4, uw4, iw4);
    gather_kernel<1><<<gatherGrid, B, 0, stream>>>(offs, col, dinv, g_a, g_b, out4, uw4, iw4);
    gather_kernel<2><<<gatherGrid, B, 0, stream>>>(offs, col, dinv, g_b, nullptr, out4, uw4, iw4);
}

// Round 4
// 535.676 us; speedup vs baseline: 1.6322x; 1.0713x over previous
//
#include <hip/hip_runtime.h>

#define N_USERS  200000
#define N_ITEMS  100000
#define N_TOTAL  300000
#define EMB_DIM  64
#define N_EDGES  4000000
#define N_LAYERS 3

// generic scan: 1024 elements per scan block
#define SCAN_CHUNK 1024

// radix partition: 512-row buckets, 8192-edge chunks
#define B2_BITS 9
#define B2_ROWS (1 << B2_BITS)                                     // 512
#define NB2 ((N_TOTAL + B2_ROWS - 1) >> B2_BITS)                   // 586
#define CHUNK_E 8192
#define NBLK ((N_EDGES + CHUNK_E - 1) / CHUNK_E)                   // 489
#define NFLAT (NB2 * NBLK)                                         // 286,554
#define NSB_FLAT ((NFLAT + SCAN_CHUNK - 1) / SCAN_CHUNK)           // 280

// edge packing: (local_row[9b] << 19) | dst[19b];  N_TOTAL < 2^19
#define DST_BITS 19
#define DST_MASK ((1 << DST_BITS) - 1)

// part2 LDS staging capacity (ints). Bucket size ~Poisson(6826), sd~83;
// 10240 is >40 sigma. Overflow -> 2-pass fallback (correctness preserved).
#define P2_CAP 10240

// gather: rows per wave
#define GR 4

typedef float f32x2 __attribute__((ext_vector_type(2)));

// ---- bf16 helpers ----
__device__ __forceinline__ unsigned bfpack(float a, float b) {
    unsigned ua = __float_as_uint(a); ua = (ua + 0x7fffu + ((ua >> 16) & 1u)) >> 16;
    unsigned ub = __float_as_uint(b); ub = (ub + 0x7fffu + ((ub >> 16) & 1u)) >> 16;
    return ua | (ub << 16);
}
__device__ __forceinline__ float bflo(unsigned u) { return __uint_as_float(u << 16); }
__device__ __forceinline__ float bfhi(unsigned u) { return __uint_as_float(u & 0xffff0000u); }
__device__ __forceinline__ f32x2 bf2(unsigned u) {
    f32x2 t; t.x = bflo(u); t.y = bfhi(u); return t;   // candidates for v_pk_add_f32 fusion
}

// ---------------- 2-level scan (block-sum correction folded into consumers) ----
__global__ void scanA_g(const int* __restrict__ in, int* __restrict__ out,
                        int* __restrict__ bsums, int n) {
    __shared__ int lds[256];
    int t = threadIdx.x, b = blockIdx.x;
    int base = b * SCAN_CHUNK + t * 4;
    int v[4];
#pragma unroll
    for (int k = 0; k < 4; ++k)
        v[k] = (base + k < n) ? in[base + k] : 0;
    int s = v[0] + v[1] + v[2] + v[3];
    lds[t] = s;
    __syncthreads();
    for (int off = 1; off < 256; off <<= 1) {
        int x = (t >= off) ? lds[t - off] : 0;
        __syncthreads();
        lds[t] += x;
        __syncthreads();
    }
    int inc = lds[t];
    int exc = inc - s;
    if (t == 255) bsums[b] = inc;
    int run = exc;
#pragma unroll
    for (int k = 0; k < 4; ++k) {
        if (base + k < n) out[base + k] = run;
        run += v[k];
    }
}

__global__ void scanB_g(int* __restrict__ bsums, int nb, int* __restrict__ total_out) {
    __shared__ int lds[512];
    int t = threadIdx.x;
    int v = (t < nb) ? bsums[t] : 0;
    lds[t] = v;
    __syncthreads();
    for (int o = 1; o < 512; o <<= 1) {
        int x = (t >= o) ? lds[t - o] : 0;
        __syncthreads();
        lds[t] += x;
        __syncthreads();
    }
    if (t < nb) bsums[t] = lds[t] - v;       // exclusive
    if (total_out && t == nb - 1) *total_out = lds[t];
}

// ---- partition phase A: per-(block,bucket) counts via LDS; int4 edge loads ----
__global__ __launch_bounds__(512) void partA_kernel(const int* __restrict__ src,
                                                    int* __restrict__ bcnt) {
    __shared__ int lcnt[NB2];
    int blk = blockIdx.x, t = threadIdx.x;
    for (int i = t; i < NB2; i += 512) lcnt[i] = 0;
    __syncthreads();
    int base = blk * CHUNK_E;
    int end = base + CHUNK_E; if (end > N_EDGES) end = N_EDGES;
    for (int e = base + 4 * t; e < end; e += 4 * 512) {
        int4 s4 = *(const int4*)(src + e);
        atomicAdd(&lcnt[s4.x >> B2_BITS], 1);
        atomicAdd(&lcnt[s4.y >> B2_BITS], 1);
        atomicAdd(&lcnt[s4.z >> B2_BITS], 1);
        atomicAdd(&lcnt[s4.w >> B2_BITS], 1);
    }
    __syncthreads();
    for (int i = t; i < NB2; i += 512)
        bcnt[(size_t)i * NBLK + blk] = lcnt[i];
}

// ---- partition phase C: write packed edges into block-private ranges ----
__global__ __launch_bounds__(512) void partC_kernel(const int* __restrict__ src,
                                                    const int* __restrict__ dst,
                                                    const int* __restrict__ boffs,
                                                    const int* __restrict__ bs2,
                                                    int* __restrict__ edgebuf) {
    __shared__ int lcur[NB2];
    int blk = blockIdx.x, t = threadIdx.x;
    for (int i = t; i < NB2; i += 512) {
        size_t f = (size_t)i * NBLK + blk;
        lcur[i] = boffs[f] + bs2[f >> 10];           // folded scanC
    }
    __syncthreads();
    int base = blk * CHUNK_E;
    int end = base + CHUNK_E; if (end > N_EDGES) end = N_EDGES;
    for (int e = base + 2 * t; e < end; e += 2 * 512) {
        int2 s2 = *(const int2*)(src + e);
        int2 d2 = *(const int2*)(dst + e);
        int pos0 = atomicAdd(&lcur[s2.x >> B2_BITS], 1);
        edgebuf[pos0] = ((s2.x & (B2_ROWS - 1)) << DST_BITS) | d2.x;
        int pos1 = atomicAdd(&lcur[s2.y >> B2_BITS], 1);
        edgebuf[pos1] = ((s2.y & (B2_ROWS - 1)) << DST_BITS) | d2.y;
    }
}

// ---- fused fine pass: per-bucket hist + scan -> offs/dinv, then scatter col ----
// Bucket edges staged in LDS (single global read); overflow -> 2-pass fallback.
__global__ __launch_bounds__(512) void part2_kernel(const int* __restrict__ boffs,
                                                    const int* __restrict__ bs2,
                                                    const int* __restrict__ edgebuf,
                                                    int* __restrict__ col,
                                                    int* __restrict__ offs,
                                                    float* __restrict__ dinv) {
    __shared__ int lhist[B2_ROWS];    // counts, then running write cursors
    __shared__ int lsums[512];
    __shared__ int lbuf[P2_CAP];
    int b = blockIdx.x;
    int base = b << B2_BITS;
    int nrows = N_TOTAL - base; if (nrows > B2_ROWS) nrows = B2_ROWS;
    int t = threadIdx.x;
    size_t f0 = (size_t)b * NBLK;
    int bstart = boffs[f0] + bs2[f0 >> 10];
    int eend;
    if (b + 1 < NB2) {
        size_t f1 = (size_t)(b + 1) * NBLK;
        eend = boffs[f1] + bs2[f1 >> 10];
    } else eend = N_EDGES;
    int cnt = eend - bstart;
    bool fits = (cnt <= P2_CAP);

    if (t < B2_ROWS) lhist[t] = 0;
    __syncthreads();
    // pass 1: per-row counts (and stage edges in LDS if they fit)
    if (fits) {
        for (int j = t; j < cnt; j += 512) {
            int e = edgebuf[bstart + j];
            lbuf[j] = e;
            atomicAdd(&lhist[e >> DST_BITS], 1);
        }
    } else {
        for (int j = bstart + t; j < eend; j += 512)
            atomicAdd(&lhist[edgebuf[j] >> DST_BITS], 1);
    }
    __syncthreads();
    // exclusive scan of 512 counts (1 per thread)
    int v = lhist[t];
    lsums[t] = v;
    __syncthreads();
    for (int o = 1; o < 512; o <<= 1) {
        int x = (t >= o) ? lsums[t - o] : 0;
        __syncthreads();
        lsums[t] += x;
        __syncthreads();
    }
    int o0 = bstart + lsums[t] - v;         // exclusive
    if (t < nrows) {
        offs[base + t] = o0;
        dinv[base + t] = rsqrtf((float)v + 1e-8f);
    }
    if (b == NB2 - 1 && t == 0) offs[N_TOTAL] = N_EDGES;
    // reuse lhist as write cursors
    lhist[t] = o0;
    __syncthreads();
    // pass 2: scatter dst into row-sorted col
    if (fits) {
        for (int j = t; j < cnt; j += 512) {
            int e = lbuf[j];
            int pos = atomicAdd(&lhist[e >> DST_BITS], 1);
            col[pos] = e & DST_MASK;
        }
    } else {
        for (int j = bstart + t; j < eend; j += 512) {
            int e = edgebuf[j];
            int pos = atomicAdd(&lhist[e >> DST_BITS], 1);
            col[pos] = e & DST_MASK;
        }
    }
}

// ---- g0 = dinv ⊙ concat(user_w, item_w), bf16x2 packed; row N_TOTAL = zeros ----
__global__ void convert_kernel(const float4* __restrict__ uw4,
                               const float4* __restrict__ iw4,
                               const float* __restrict__ dinv,
                               uint2* __restrict__ g0) {
    int i = blockIdx.x * blockDim.x + threadIdx.x;
    const int n = (N_TOTAL + 1) * 16;
    if (i < n) {
        int row = i >> 4;
        if (row >= N_TOTAL) {
            g0[i] = make_uint2(0u, 0u);      // dummy zero row
        } else {
            float4 x = (row < N_USERS) ? uw4[i] : iw4[i - N_USERS * 16];
            float di = dinv[row];
            g0[i] = make_uint2(bfpack(di * x.x, di * x.y),
                               bfpack(di * x.z, di * x.w));
        }
    }
}

// ---------------- gather SpMM on pre-scaled g tables ----------------
// h_next[row] = dinv[row] * sum_{edges} g_prev[col];  g_next = dinv * h_next.
// Each wave handles GR=4 rows; one coalesced load fetches the GR+1 offsets
// (readlane -> SGPRs) and GR dinv values; row i+1's col-index window is
// prefetched while row i's gathers are in flight (cross-row pipelining).
// 4 edge streams (16-lane quarters); lane r of quarter q covers dims 4r..4r+3
// via one dwordx2 load; 16 edges per inner iter => 4 gathers in flight.
// Out-of-range shfl slots hold the zero-row index N_TOTAL (no bounds logic).
// MODE 0: out = x + h.  MODE 1: out += h.  MODE 2: out = (out+h)/4, no g_next.
template <int MODE>
__global__ __launch_bounds__(256) void gather_kernel(
        const int* __restrict__ offs,
        const int* __restrict__ col,
        const float* __restrict__ dinv,
        const unsigned* __restrict__ gprev,
        unsigned* __restrict__ gnext,
        float4* __restrict__ out4,
        const float4* __restrict__ uw4,
        const float4* __restrict__ iw4) {
    int wid  = blockIdx.x * 4 + (threadIdx.x >> 6);
    int base_row = wid * GR;
    int lane = threadIdx.x & 63;
    int q    = lane >> 4;          // quarter = edge stream
    int r    = lane & 15;          // dims 4r..4r+3
    // coalesced: lanes 0..GR hold offs[base_row..base_row+GR]; 0..GR-1 hold dinv
    int li = lane < GR ? lane : GR;
    int off_l = offs[base_row + li];
    float dv  = dinv[base_row + (lane < GR ? lane : GR - 1)];

    // prefetch row 0's first col window
    int s0 = __builtin_amdgcn_readlane(off_l, 0);
    int e0 = __builtin_amdgcn_readlane(off_l, 1);
    int myc_cur = (lane < e0 - s0) ? col[s0 + lane] : N_TOTAL;

#pragma unroll
    for (int i = 0; i < GR; ++i) {
        int start = __builtin_amdgcn_readlane(off_l, i);
        int end   = __builtin_amdgcn_readlane(off_l, i + 1);
        // prefetch next row's first window before draining this row's gathers
        int myc_next = N_TOTAL;
        if (i + 1 < GR) {
            int sn = __builtin_amdgcn_readlane(off_l, i + 1);
            int en = __builtin_amdgcn_readlane(off_l, i + 2);
            myc_next = (lane < en - sn) ? col[sn + lane] : N_TOTAL;
        }
        f32x2 acc01 = {0.f, 0.f};
        f32x2 acc23 = {0.f, 0.f};
        int n = end - start; if (n > 64) n = 64;
        for (int k0 = 0; k0 < n; k0 += 16) {
            int c0 = __shfl(myc_cur, k0 + q);
            int c1 = __shfl(myc_cur, k0 + 4 + q);
            int c2 = __shfl(myc_cur, k0 + 8 + q);
            int c3 = __shfl(myc_cur, k0 + 12 + q);
            uint2 u0 = *(const uint2*)(gprev + ((size_t)(unsigned)c0 << 5) + 2 * r);
            uint2 u1 = *(const uint2*)(gprev + ((size_t)(unsigned)c1 << 5) + 2 * r);
            uint2 u2 = *(const uint2*)(gprev + ((size_t)(unsigned)c2 << 5) + 2 * r);
            uint2 u3 = *(const uint2*)(gprev + ((size_t)(unsigned)c3 << 5) + 2 * r);
            acc01 += bf2(u0.x); acc23 += bf2(u0.y);
            acc01 += bf2(u1.x); acc23 += bf2(u1.y);
            acc01 += bf2(u2.x); acc23 += bf2(u2.y);
            acc01 += bf2(u3.x); acc23 += bf2(u3.y);
        }
        // rare: rows with degree > 64
        for (int cb = start + 64; cb < end; cb += 64) {
            int rem = end - cb;
            int nn = rem > 64 ? 64 : rem;
            int myc = (lane < rem) ? col[cb + lane] : N_TOTAL;
            for (int k0 = 0; k0 < nn; k0 += 16) {
                int c0 = __shfl(myc, k0 + q);
                int c1 = __shfl(myc, k0 + 4 + q);
                int c2 = __shfl(myc, k0 + 8 + q);
                int c3 = __shfl(myc, k0 + 12 + q);
                uint2 u0 = *(const uint2*)(gprev + ((size_t)(unsigned)c0 << 5) + 2 * r);
                uint2 u1 = *(const uint2*)(gprev + ((size_t)(unsigned)c1 << 5) + 2 * r);
                uint2 u2 = *(const uint2*)(gprev + ((size_t)(unsigned)c2 << 5) + 2 * r);
                uint2 u3 = *(const uint2*)(gprev + ((size_t)(unsigned)c3 << 5) + 2 * r);
                acc01 += bf2(u0.x); acc23 += bf2(u0.y);
                acc01 += bf2(u1.x); acc23 += bf2(u1.y);
                acc01 += bf2(u2.x); acc23 += bf2(u2.y);
                acc01 += bf2(u3.x); acc23 += bf2(u3.y);
            }
        }
        float a0 = acc01.x, a1 = acc01.y, a2 = acc23.x, a3 = acc23.y;
        a0 += __shfl_xor(a0, 16);
        a1 += __shfl_xor(a1, 16);
        a2 += __shfl_xor(a2, 16);
        a3 += __shfl_xor(a3, 16);
        a0 += __shfl_xor(a0, 32);
        a1 += __shfl_xor(a1, 32);
        a2 += __shfl_xor(a2, 32);
        a3 += __shfl_xor(a3, 32);
        float di = __shfl(dv, i);
        if (lane < 16) {
            int row = base_row + i;
            float h0 = di * a0, h1 = di * a1, h2 = di * a2, h3 = di * a3;
            int p = row * 16 + r;
            if (MODE == 0) {
                float4 x = (row < N_USERS) ? uw4[p] : iw4[p - N_USERS * 16];
                ((uint2*)gnext)[p] = make_uint2(bfpack(di * h0, di * h1),
                                                bfpack(di * h2, di * h3));
                out4[p] = make_float4(x.x + h0, x.y + h1, x.z + h2, x.w + h3);
            } else if (MODE == 1) {
                float4 o = out4[p];
                ((uint2*)gnext)[p] = make_uint2(bfpack(di * h0, di * h1),
                                                bfpack(di * h2, di * h3));
                out4[p] = make_float4(o.x + h0, o.y + h1, o.z + h2, o.w + h3);
            } else {
                float4 o = out4[p];
                out4[p] = make_float4((o.x + h0) * 0.25f, (o.y + h1) * 0.25f,
                                      (o.z + h2) * 0.25f, (o.w + h3) * 0.25f);
            }
        }
        myc_cur = myc_next;
    }
    // maintain the zero row of the table the NEXT kernel gathers from
    if (MODE != 2) {
        if (blockIdx.x == 0 && threadIdx.x < 32)
            gnext[N_TOTAL * 32 + threadIdx.x] = 0u;
    }
}

extern "C" void kernel_launch(void* const* d_in, const int* in_sizes, int n_in,
                              void* d_out, int out_size, void* d_ws, size_t ws_size,
                              hipStream_t stream) {
    const float* user_w = (const float*)d_in[0];
    const float* item_w = (const float*)d_in[1];
    const int*   src    = (const int*)d_in[2];
    const int*   dst    = (const int*)d_in[3];
    float* out = (float*)d_out;
    (void)in_sizes; (void)n_in; (void)out_size; (void)ws_size;

    char* ws = (char*)d_ws;
    size_t off = 0;
    auto alloc = [&](size_t bytes) {
        char* p = ws + off;
        off = (off + bytes + 255) & ~(size_t)255;
        return p;
    };
    int*      offs   = (int*)     alloc((size_t)(N_TOTAL + 1) * 4);
    int*      bcnt   = (int*)     alloc((size_t)NFLAT * 4);              // 1.15 MB
    int*      boffs  = (int*)     alloc((size_t)NFLAT * 4);              // 1.15 MB
    int*      bs2    = (int*)     alloc((size_t)NSB_FLAT * 4);
    int*      col    = (int*)     alloc((size_t)N_EDGES * 4);            // 16 MB
    int*      edgebuf= (int*)     alloc((size_t)N_EDGES * 4);            // 16 MB (packed)
    float*    dinv   = (float*)   alloc((size_t)N_TOTAL * 4);
    unsigned* g0     = (unsigned*)alloc((size_t)(N_TOTAL + 1) * 32 * 4); // 38.4 MB
    unsigned* g_a    = (unsigned*)alloc((size_t)(N_TOTAL + 1) * 32 * 4); // 38.4 MB
    unsigned* g_b    = (unsigned*)alloc((size_t)(N_TOTAL + 1) * 32 * 4); // 38.4 MB

    const int B = 256;
    const int gatherGrid = N_TOTAL / (4 * GR);   // 18750

    // radix partition into 512-row buckets (block-private write ranges)
    partA_kernel<<<NBLK, 512, 0, stream>>>(src, bcnt);
    scanA_g<<<NSB_FLAT, B, 0, stream>>>(bcnt, boffs, bs2, NFLAT);
    scanB_g<<<1, 512, 0, stream>>>(bs2, NSB_FLAT, nullptr);
    partC_kernel<<<NBLK, 512, 0, stream>>>(src, dst, boffs, bs2, edgebuf);
    // fused: per-bucket hist + scan -> offs, dinv; scatter col (LDS-staged)
    part2_kernel<<<NB2, 512, 0, stream>>>(boffs, bs2, edgebuf, col, offs, dinv);

    // g0 = dinv * x (bf16), plus zero dummy row
    convert_kernel<<<((N_TOTAL + 1) * 16 + B - 1) / B, B, 0, stream>>>(
        (const float4*)user_w, (const float4*)item_w, dinv, (uint2*)g0);

    const float4* uw4 = (const float4*)user_w;
    const float4* iw4 = (const float4*)item_w;
    float4* out4 = (float4*)out;
    gather_kernel<0><<<gatherGrid, B, 0, stream>>>(offs, col, dinv, g0,  g_a, out4, uw4, iw4);
    gather_kernel<1><<<gatherGrid, B, 0, stream>>>(offs, col, dinv, g_a, g_b, out4, uw4, iw4);
    gather_kernel<2><<<gatherGrid, B, 0, stream>>>(offs, col, dinv, g_b, nullptr, out4, uw4, iw4);
}